// Round 1
// baseline (448.760 us; speedup 1.0000x reference)
//
#include <hip/hip_runtime.h>
#include <stdint.h>

typedef short bf16x8 __attribute__((ext_vector_type(8)));
typedef float f32x4 __attribute__((ext_vector_type(4)));
typedef unsigned long long u64;

__device__ __forceinline__ float bf2f(unsigned short u){
  union { unsigned int i; float f; } c; c.i = ((unsigned int)u) << 16; return c.f;
}
__device__ __forceinline__ unsigned short f2bf(float f){
  unsigned int x = __float_as_uint(f);
  return (unsigned short)((x + 0x7FFFu + ((x >> 16) & 1u)) >> 16);
}

union FragU { bf16x8 v; uint4 u; };

// ---- workspace offsets (bytes) ----
#define OFF_WVT 0ull                   // [256][64] bf16  (Wv^T)
#define OFF_WGT 32768ull               // [256][64] bf16  (Wg^T)
#define OFF_WOT 65536ull               // [64][256] bf16  (Wo^T)
#define OFF_W   131072ull              // [8][512][512] bf16 softmax weights
#define OFF_VT  8388608ull             // [8][16384][512] bf16 : v_t[h][s*32+c][j]
#define OFF_O   142606336ull           // [512][512][256] bf16 : o[s][i][h*32+c]

// =================== K0: weight convert + transpose ===================
__global__ __launch_bounds__(256) void k0_weights(const float* __restrict__ Wv,
                                                  const float* __restrict__ Wg,
                                                  const float* __restrict__ Wo,
                                                  unsigned short* __restrict__ wvt,
                                                  unsigned short* __restrict__ wgt,
                                                  unsigned short* __restrict__ wot){
  int idx = blockIdx.x * 256 + threadIdx.x;
  if (idx < 16384){ int k = idx >> 8, n = idx & 255; wvt[n * 64 + k] = f2bf(Wv[idx]); }
  else if (idx < 32768){ int j = idx - 16384; int k = j >> 8, n = j & 255; wgt[n * 64 + k] = f2bf(Wg[j]); }
  else if (idx < 49152){ int j = idx - 32768; int k = j >> 6, n = j & 63;  wot[n * 256 + k] = f2bf(Wo[j]); }
}

// =================== K1: pair LN -> bias -> softmax_j -> w[h][i][j] ===================
__global__ __launch_bounds__(256) void k1_pairw(const float* __restrict__ pair,
                                                const float* __restrict__ lnw,
                                                const float* __restrict__ lnb,
                                                const float* __restrict__ Wb,
                                                unsigned short* __restrict__ wout){
  __shared__ float b_lds[512 * 9];
  const int tid = threadIdx.x, lane = tid & 63, wave = tid >> 6;
  const int i = blockIdx.x;
  const int c0 = lane, c1 = lane + 64;
  float wb0[8], wb1[8];
#pragma unroll
  for (int h = 0; h < 8; ++h){ wb0[h] = Wb[c0 * 8 + h]; wb1[h] = Wb[c1 * 8 + h]; }
  const float lw0 = lnw[c0], lb0v = lnb[c0], lw1 = lnw[c1], lb1v = lnb[c1];

  for (int jj = 0; jj < 64; ++jj){
    int jA = jj * 8 + wave * 2;
#pragma unroll
    for (int r = 0; r < 2; ++r){
      int j = jA + r;
      size_t base = ((size_t)i * 512 + j) * 128;
      float x0 = pair[base + c0], x1 = pair[base + c1];
      float s = x0 + x1, q = x0 * x0 + x1 * x1;
#pragma unroll
      for (int o = 1; o < 64; o <<= 1){ s += __shfl_xor(s, o); q += __shfl_xor(q, o); }
      float mean = s * (1.f / 128.f);
      float var = q * (1.f / 128.f) - mean * mean;
      float rstd = rsqrtf(var + 1e-5f);
      float xn0 = (x0 - mean) * rstd * lw0 + lb0v;
      float xn1 = (x1 - mean) * rstd * lw1 + lb1v;
      float ph[8];
#pragma unroll
      for (int h = 0; h < 8; ++h) ph[h] = xn0 * wb0[h] + xn1 * wb1[h];
      // reduce-scatter folds: 10 shfl instead of 48
#pragma unroll
      for (int u = 0; u < 4; ++u){
        float snd = (lane & 1) ? ph[u] : ph[u + 4];
        float t = __shfl_xor(snd, 1);
        ph[u] = ((lane & 1) ? ph[u + 4] : ph[u]) + t;
      }
#pragma unroll
      for (int u = 0; u < 2; ++u){
        float snd = (lane & 2) ? ph[u] : ph[u + 2];
        float t = __shfl_xor(snd, 2);
        ph[u] = ((lane & 2) ? ph[u + 2] : ph[u]) + t;
      }
      {
        float snd = (lane & 4) ? ph[0] : ph[1];
        float t = __shfl_xor(snd, 4);
        ph[0] = ((lane & 4) ? ph[1] : ph[0]) + t;
      }
      ph[0] += __shfl_xor(ph[0], 8);
      ph[0] += __shfl_xor(ph[0], 16);
      ph[0] += __shfl_xor(ph[0], 32);
      if (lane < 8){
        int hL = ((lane & 1) << 2) | (lane & 2) | ((lane >> 2) & 1);
        b_lds[j * 9 + hL] = ph[0];
      }
    }
  }
  __syncthreads();
  // softmax over j per head; wave w handles heads 2w, 2w+1
#pragma unroll
  for (int hh = 0; hh < 2; ++hh){
    int h = wave * 2 + hh;
    float e[8]; float m = -3.4e38f;
#pragma unroll
    for (int t = 0; t < 8; ++t){ e[t] = b_lds[(lane + 64 * t) * 9 + h]; m = fmaxf(m, e[t]); }
#pragma unroll
    for (int o = 1; o < 64; o <<= 1) m = fmaxf(m, __shfl_xor(m, o));
    float sum = 0.f;
#pragma unroll
    for (int t = 0; t < 8; ++t){ e[t] = __expf(e[t] - m); sum += e[t]; }
#pragma unroll
    for (int o = 1; o < 64; o <<= 1) sum += __shfl_xor(sum, o);
    float inv = 1.0f / sum;
    size_t base = ((size_t)(h * 512 + i)) * 512;
#pragma unroll
    for (int t = 0; t < 8; ++t) wout[base + lane + 64 * t] = f2bf(e[t] * inv);
  }
}

// =================== K2: msa LN -> v = mn@Wv -> v_t[h][s*32+c][j] ===================
// grid (2048, 2): bx -> (s, n0), by -> 128-col slice of the 256 v-channels
__global__ __launch_bounds__(256) void k2_v(const float* __restrict__ msa,
                                            const float* __restrict__ lnw,
                                            const float* __restrict__ lnb,
                                            const unsigned short* __restrict__ wvt,
                                            unsigned short* __restrict__ vt){
  __shared__ unsigned short smem[18432];   // [0,9216): mnb [128][72]; [9216,18432): wvt slice [128][72]; epilogue overlay [128][136]
  __shared__ float lnw_s[64], lnb_s[64];
  const int tid = threadIdx.x, lane = tid & 63, wave = tid >> 6;
  const int bx = blockIdx.x;
  const int sIdx = bx >> 2, n0 = (bx & 3) * 128;
  const int cb = blockIdx.y * 128;
  const int g = lane >> 4, l15 = lane & 15;
  if (tid < 64){ lnw_s[tid] = lnw[tid]; lnb_s[tid] = lnb[tid]; }
  const int row = tid >> 1, half = tid & 1;
  float4 xv[8];
  {
    const float4* src = (const float4*)(msa + ((size_t)(sIdx * 512 + n0 + row)) * 64 + half * 32);
#pragma unroll
    for (int u = 0; u < 8; ++u) xv[u] = src[u];
  }
  { // stage Wv^T slice
    const uint4* src = (const uint4*)(wvt + (size_t)(cb + row) * 64 + half * 32);
    uint4* dst = (uint4*)&smem[9216 + row * 72 + half * 32];
#pragma unroll
    for (int u = 0; u < 4; ++u) dst[u] = src[u];
  }
  float sS = 0.f, qS = 0.f;
#pragma unroll
  for (int u = 0; u < 8; ++u){
    sS += xv[u].x + xv[u].y + xv[u].z + xv[u].w;
    qS += xv[u].x * xv[u].x + xv[u].y * xv[u].y + xv[u].z * xv[u].z + xv[u].w * xv[u].w;
  }
  sS += __shfl_xor(sS, 1); qS += __shfl_xor(qS, 1);
  const float mean = sS * (1.f / 64.f);
  const float var = qS * (1.f / 64.f) - mean * mean;
  const float rstd = rsqrtf(var + 1e-5f);
  __syncthreads();
  {
    unsigned int pk[16];
#pragma unroll
    for (int u = 0; u < 8; ++u){
      const int cbase = half * 32 + u * 4;
      float a0 = (xv[u].x - mean) * rstd * lnw_s[cbase + 0] + lnb_s[cbase + 0];
      float a1 = (xv[u].y - mean) * rstd * lnw_s[cbase + 1] + lnb_s[cbase + 1];
      float a2 = (xv[u].z - mean) * rstd * lnw_s[cbase + 2] + lnb_s[cbase + 2];
      float a3 = (xv[u].w - mean) * rstd * lnw_s[cbase + 3] + lnb_s[cbase + 3];
      pk[u * 2]     = (unsigned)f2bf(a0) | ((unsigned)f2bf(a1) << 16);
      pk[u * 2 + 1] = (unsigned)f2bf(a2) | ((unsigned)f2bf(a3) << 16);
    }
    uint4* dst = (uint4*)&smem[row * 72 + half * 32];
#pragma unroll
    for (int u = 0; u < 4; ++u) dst[u] = make_uint4(pk[u * 4], pk[u * 4 + 1], pk[u * 4 + 2], pk[u * 4 + 3]);
  }
  __syncthreads();
  const int wm = wave >> 1, wn = wave & 1;
  const f32x4 z = {0.f, 0.f, 0.f, 0.f};
  f32x4 acc[4][4];
#pragma unroll
  for (int a = 0; a < 4; ++a)
#pragma unroll
    for (int b = 0; b < 4; ++b) acc[a][b] = z;
#pragma unroll
  for (int kk = 0; kk < 64; kk += 32){
    bf16x8 av[4], bv[4];
#pragma unroll
    for (int mf = 0; mf < 4; ++mf){
      FragU f; f.u = *(const uint4*)&smem[(wm * 64 + mf * 16 + l15) * 72 + kk + 8 * g];
      av[mf] = f.v;
    }
#pragma unroll
    for (int nf = 0; nf < 4; ++nf){
      FragU f; f.u = *(const uint4*)&smem[9216 + (wn * 64 + nf * 16 + l15) * 72 + kk + 8 * g];
      bv[nf] = f.v;
    }
#pragma unroll
    for (int mf = 0; mf < 4; ++mf)
#pragma unroll
      for (int nf = 0; nf < 4; ++nf)
        acc[mf][nf] = __builtin_amdgcn_mfma_f32_16x16x32_bf16(av[mf], bv[nf], acc[mf][nf], 0, 0, 0);
  }
  __syncthreads();
  // epilogue transpose into overlay [hc][n]
#pragma unroll
  for (int nf = 0; nf < 4; ++nf){
    int hcL = wn * 64 + nf * 16 + l15;
#pragma unroll
    for (int mf = 0; mf < 4; ++mf){
      int nbase = wm * 64 + mf * 16 + 4 * g;
      u64 qv = (u64)f2bf(acc[mf][nf][0])
             | ((u64)f2bf(acc[mf][nf][1]) << 16)
             | ((u64)f2bf(acc[mf][nf][2]) << 32)
             | ((u64)f2bf(acc[mf][nf][3]) << 48);
      *(u64*)&smem[hcL * 136 + nbase] = qv;
    }
  }
  __syncthreads();
  { // coalesced global write: v_t[h][s*32+c][n]
    int hcL = tid >> 1, nh = tid & 1;
    int hc = cb + hcL;
    int hIdx = hc >> 5, c = hc & 31;
    unsigned short* dst = vt + ((size_t)(hIdx * 16384 + sIdx * 32 + c)) * 512 + n0 + nh * 64;
    const uint4* src = (const uint4*)&smem[hcL * 136 + nh * 64];
#pragma unroll
    for (int u = 0; u < 8; ++u) ((uint4*)dst)[u] = src[u];
  }
}

// =================== K3: per-head GEMM o[i, s*32+c] = sum_j w[h][i][j] * v_t[h][sc][j] ===================
// grid (128, 4, 8): bx -> sc-tile, by -> i-tile, bz -> head
__global__ __launch_bounds__(256) void k3_attn(const unsigned short* __restrict__ wp,
                                               const unsigned short* __restrict__ vt,
                                               unsigned short* __restrict__ o){
  __shared__ unsigned short A_s[128 * 72];
  __shared__ unsigned short B_s[128 * 72];
  const int tid = threadIdx.x, lane = tid & 63, wave = tid >> 6;
  const int sc0 = blockIdx.x * 128, i0 = blockIdx.y * 128, h = blockIdx.z;
  const int wm = wave >> 1, wn = wave & 1;
  const int g = lane >> 4, l15 = lane & 15;
  const int srow = tid >> 1, shalf = tid & 1;
  const unsigned short* wbase = wp + ((size_t)(h * 512 + i0 + srow)) * 512 + shalf * 32;
  const unsigned short* vbase = vt + ((size_t)(h * 16384 + sc0 + srow)) * 512 + shalf * 32;
  const f32x4 z = {0.f, 0.f, 0.f, 0.f};
  f32x4 acc[4][4];
#pragma unroll
  for (int a = 0; a < 4; ++a)
#pragma unroll
    for (int b = 0; b < 4; ++b) acc[a][b] = z;

  for (int kt = 0; kt < 8; ++kt){
    const int j0 = kt * 64;
    __syncthreads();
    {
      const uint4* ga = (const uint4*)(wbase + j0);
      uint4* da = (uint4*)&A_s[srow * 72 + shalf * 32];
#pragma unroll
      for (int u = 0; u < 4; ++u) da[u] = ga[u];
      const uint4* gb = (const uint4*)(vbase + j0);
      uint4* db = (uint4*)&B_s[srow * 72 + shalf * 32];
#pragma unroll
      for (int u = 0; u < 4; ++u) db[u] = gb[u];
    }
    __syncthreads();
#pragma unroll
    for (int kk = 0; kk < 64; kk += 32){
      bf16x8 av[4], bv[4];
#pragma unroll
      for (int mf = 0; mf < 4; ++mf){
        FragU f; f.u = *(const uint4*)&A_s[(wm * 64 + mf * 16 + l15) * 72 + kk + 8 * g];
        av[mf] = f.v;
      }
#pragma unroll
      for (int nf = 0; nf < 4; ++nf){
        FragU f; f.u = *(const uint4*)&B_s[(wn * 64 + nf * 16 + l15) * 72 + kk + 8 * g];
        bv[nf] = f.v;
      }
#pragma unroll
      for (int mf = 0; mf < 4; ++mf)
#pragma unroll
        for (int nf = 0; nf < 4; ++nf)
          acc[mf][nf] = __builtin_amdgcn_mfma_f32_16x16x32_bf16(av[mf], bv[nf], acc[mf][nf], 0, 0, 0);
    }
  }
  // epilogue: o[s][i][h*32+c]
#pragma unroll
  for (int nf = 0; nf < 4; ++nf){
    int col_sc = sc0 + wn * 64 + nf * 16 + l15;
    int sIdx = col_sc >> 5, c = col_sc & 31;
#pragma unroll
    for (int mf = 0; mf < 4; ++mf){
      int rbase = i0 + wm * 64 + mf * 16 + 4 * g;
#pragma unroll
      for (int e = 0; e < 4; ++e)
        o[((size_t)(sIdx * 512 + rbase + e)) * 256 + h * 32 + c] = f2bf(acc[mf][nf][e]);
    }
  }
}

// =================== K4: fused LN -> G=mn@Wg -> sigmoid -> gate*o -> @Wo -> out ===================
// grid 4096: 64 consecutive rows r = s*512 + i per block
__global__ __launch_bounds__(256) void k4_out(const float* __restrict__ msa,
                                              const float* __restrict__ lnw,
                                              const float* __restrict__ lnb,
                                              const unsigned short* __restrict__ ot,
                                              const unsigned short* __restrict__ wgt,
                                              const unsigned short* __restrict__ wot,
                                              float* __restrict__ out){
  __shared__ unsigned short o_s[64 * 256];
  __shared__ unsigned short mnb[64 * 72];
  __shared__ unsigned short X_s[64 * 40];
  __shared__ unsigned short wg_s[32 * 72];
  __shared__ unsigned short wo_s[64 * 40];
  __shared__ float lnw_s[64], lnb_s[64];
  const int tid = threadIdx.x, lane = tid & 63, wave = tid >> 6;
  const int r0 = blockIdx.x * 64;
  const int g = lane >> 4, l15 = lane & 15;
  if (tid < 64){ lnw_s[tid] = lnw[tid]; lnb_s[tid] = lnb[tid]; }
  { // stage o tile
    int row = tid >> 2, q = tid & 3;
    const uint4* src = (const uint4*)(ot + ((size_t)(r0 + row)) * 256 + q * 64);
    uint4* dst = (uint4*)&o_s[row * 256 + q * 64];
#pragma unroll
    for (int u = 0; u < 8; ++u) dst[u] = src[u];
  }
  // LayerNorm of msa rows (4 threads per row, 16 ch each)
  const int lrow = tid >> 2, lq = tid & 3;
  float4 xv[4];
  {
    const float4* src = (const float4*)(msa + ((size_t)(r0 + lrow)) * 64 + lq * 16);
#pragma unroll
    for (int u = 0; u < 4; ++u) xv[u] = src[u];
  }
  float sS = 0.f, qS = 0.f;
#pragma unroll
  for (int u = 0; u < 4; ++u){
    sS += xv[u].x + xv[u].y + xv[u].z + xv[u].w;
    qS += xv[u].x * xv[u].x + xv[u].y * xv[u].y + xv[u].z * xv[u].z + xv[u].w * xv[u].w;
  }
  sS += __shfl_xor(sS, 1); qS += __shfl_xor(qS, 1);
  sS += __shfl_xor(sS, 2); qS += __shfl_xor(qS, 2);
  const float mean = sS * (1.f / 64.f);
  const float var = qS * (1.f / 64.f) - mean * mean;
  const float rstd = rsqrtf(var + 1e-5f);
  __syncthreads();
  {
    unsigned int pk[8];
#pragma unroll
    for (int u = 0; u < 4; ++u){
      const int cbase = lq * 16 + u * 4;
      float a0 = (xv[u].x - mean) * rstd * lnw_s[cbase + 0] + lnb_s[cbase + 0];
      float a1 = (xv[u].y - mean) * rstd * lnw_s[cbase + 1] + lnb_s[cbase + 1];
      float a2 = (xv[u].z - mean) * rstd * lnw_s[cbase + 2] + lnb_s[cbase + 2];
      float a3 = (xv[u].w - mean) * rstd * lnw_s[cbase + 3] + lnb_s[cbase + 3];
      pk[u * 2]     = (unsigned)f2bf(a0) | ((unsigned)f2bf(a1) << 16);
      pk[u * 2 + 1] = (unsigned)f2bf(a2) | ((unsigned)f2bf(a3) << 16);
    }
    uint4* dst = (uint4*)&mnb[lrow * 72 + lq * 16];
    dst[0] = make_uint4(pk[0], pk[1], pk[2], pk[3]);
    dst[1] = make_uint4(pk[4], pk[5], pk[6], pk[7]);
  }
  const int wm = wave >> 1, wn = wave & 1;
  const f32x4 z = {0.f, 0.f, 0.f, 0.f};
  f32x4 accO[2][2];
  accO[0][0] = z; accO[0][1] = z; accO[1][0] = z; accO[1][1] = z;

  for (int h = 0; h < 8; ++h){
    __syncthreads();
    if (tid < 64){
      int row = tid >> 1, hf = tid & 1;
      const uint4* src = (const uint4*)(wgt + (size_t)(h * 32 + row) * 64 + hf * 32);
      uint4* dst = (uint4*)&wg_s[row * 72 + hf * 32];
#pragma unroll
      for (int u = 0; u < 4; ++u) dst[u] = src[u];
    } else if (tid < 192){
      int t = tid - 64; int row = t >> 1, hf = t & 1;
      const uint4* src = (const uint4*)(wot + (size_t)row * 256 + h * 32 + hf * 16);
      uint4* dst = (uint4*)&wo_s[row * 40 + hf * 16];
      dst[0] = src[0]; dst[1] = src[1];
    }
    __syncthreads();
    // G = mnb @ Wg_h  (wave handles rows [16w,16w+16), cols 0..31)
    f32x4 gacc[2]; gacc[0] = z; gacc[1] = z;
#pragma unroll
    for (int kk = 0; kk < 64; kk += 32){
      FragU a; a.u = *(const uint4*)&mnb[(wave * 16 + l15) * 72 + kk + 8 * g];
#pragma unroll
      for (int nf = 0; nf < 2; ++nf){
        FragU b; b.u = *(const uint4*)&wg_s[(nf * 16 + l15) * 72 + kk + 8 * g];
        gacc[nf] = __builtin_amdgcn_mfma_f32_16x16x32_bf16(a.v, b.v, gacc[nf], 0, 0, 0);
      }
    }
    // gate -> X_s
#pragma unroll
    for (int nf = 0; nf < 2; ++nf){
#pragma unroll
      for (int e = 0; e < 4; ++e){
        int row = wave * 16 + 4 * g + e;
        int col = nf * 16 + l15;
        float gv = 1.0f / (1.0f + __expf(-gacc[nf][e]));
        float ov = bf2f(o_s[row * 256 + h * 32 + col]);
        X_s[row * 40 + col] = f2bf(gv * ov);
      }
    }
    __syncthreads();
    // out += X_h @ Wo_h
#pragma unroll
    for (int mf = 0; mf < 2; ++mf){
      FragU a; a.u = *(const uint4*)&X_s[(wm * 32 + mf * 16 + l15) * 40 + 8 * g];
#pragma unroll
      for (int nf = 0; nf < 2; ++nf){
        FragU b; b.u = *(const uint4*)&wo_s[(wn * 32 + nf * 16 + l15) * 40 + 8 * g];
        accO[mf][nf] = __builtin_amdgcn_mfma_f32_16x16x32_bf16(a.v, b.v, accO[mf][nf], 0, 0, 0);
      }
    }
  }
#pragma unroll
  for (int mf = 0; mf < 2; ++mf)
#pragma unroll
    for (int nf = 0; nf < 2; ++nf)
#pragma unroll
      for (int e = 0; e < 4; ++e){
        int row = wm * 32 + mf * 16 + 4 * g + e;
        int col = wn * 32 + nf * 16 + l15;
        out[((size_t)(r0 + row)) * 64 + col] = accO[mf][nf][e];
      }
}

extern "C" void kernel_launch(void* const* d_in, const int* in_sizes, int n_in,
                              void* d_out, int out_size, void* d_ws, size_t ws_size,
                              hipStream_t stream){
  const float* msa       = (const float*)d_in[0];
  const float* pair      = (const float*)d_in[1];
  const float* ln_msa_w  = (const float*)d_in[2];
  const float* ln_msa_b  = (const float*)d_in[3];
  const float* ln_pair_w = (const float*)d_in[4];
  const float* ln_pair_b = (const float*)d_in[5];
  const float* Wv        = (const float*)d_in[6];
  const float* Wb        = (const float*)d_in[7];
  const float* Wg        = (const float*)d_in[8];
  const float* Wo        = (const float*)d_in[9];
  float* out = (float*)d_out;
  char* ws = (char*)d_ws;
  unsigned short* wvt = (unsigned short*)(ws + OFF_WVT);
  unsigned short* wgt = (unsigned short*)(ws + OFF_WGT);
  unsigned short* wot = (unsigned short*)(ws + OFF_WOT);
  unsigned short* wsm = (unsigned short*)(ws + OFF_W);
  unsigned short* vt  = (unsigned short*)(ws + OFF_VT);
  unsigned short* obuf= (unsigned short*)(ws + OFF_O);

  hipLaunchKernelGGL(k0_weights, dim3(192), dim3(256), 0, stream, Wv, Wg, Wo, wvt, wgt, wot);
  hipLaunchKernelGGL(k1_pairw,  dim3(512), dim3(256), 0, stream, pair, ln_pair_w, ln_pair_b, Wb, wsm);
  hipLaunchKernelGGL(k2_v,      dim3(2048, 2), dim3(256), 0, stream, msa, ln_msa_w, ln_msa_b, wvt, vt);
  hipLaunchKernelGGL(k3_attn,   dim3(128, 4, 8), dim3(256), 0, stream, wsm, vt, obuf);
  hipLaunchKernelGGL(k4_out,    dim3(4096), dim3(256), 0, stream, msa, ln_msa_w, ln_msa_b, obuf, wgt, wot, out);
}

// Round 2
// 387.747 us; speedup vs baseline: 1.1574x; 1.1574x over previous
//
#include <hip/hip_runtime.h>
#include <stdint.h>

typedef short bf16x8 __attribute__((ext_vector_type(8)));
typedef float f32x4 __attribute__((ext_vector_type(4)));
typedef unsigned long long u64;

__device__ __forceinline__ float bf2f(unsigned short u){
  union { unsigned int i; float f; } c; c.i = ((unsigned int)u) << 16; return c.f;
}
__device__ __forceinline__ unsigned short f2bf(float f){
  unsigned int x = __float_as_uint(f);
  return (unsigned short)((x + 0x7FFFu + ((x >> 16) & 1u)) >> 16);
}

union FragU { bf16x8 v; uint4 u; };

// ---- workspace offsets (bytes) ----
#define OFF_WVT 0ull                   // [256][64] bf16  (Wv^T)
#define OFF_WGT 32768ull               // [256][64] bf16  (Wg^T)
#define OFF_WOT 65536ull               // [64][256] bf16  (Wo^T)
#define OFF_W   131072ull              // [8][512][512] bf16 softmax weights
#define OFF_VT  8388608ull             // [8][16384][512] bf16 : v_t[h][s*32+c][j]  (also b fp32 scratch before K2)
#define OFF_O   142606336ull           // [512][512][256] bf16 : o[s][i][h*32+c]

// =================== K0: weight convert + transpose ===================
__global__ __launch_bounds__(256) void k0_weights(const float* __restrict__ Wv,
                                                  const float* __restrict__ Wg,
                                                  const float* __restrict__ Wo,
                                                  unsigned short* __restrict__ wvt,
                                                  unsigned short* __restrict__ wgt,
                                                  unsigned short* __restrict__ wot){
  int idx = blockIdx.x * 256 + threadIdx.x;
  if (idx < 16384){ int k = idx >> 8, n = idx & 255; wvt[n * 64 + k] = f2bf(Wv[idx]); }
  else if (idx < 32768){ int j = idx - 16384; int k = j >> 8, n = j & 255; wgt[n * 64 + k] = f2bf(Wg[j]); }
  else if (idx < 49152){ int j = idx - 32768; int k = j >> 6, n = j & 63;  wot[n * 256 + k] = f2bf(Wo[j]); }
}

// reduce-scatter fold of 8 per-lane partials; returns full h-sum on every lane,
// where h = ((lane&1)<<2) | (lane&2) | ((lane>>2)&1)
__device__ __forceinline__ float fold8(float ph[8], int lane){
#pragma unroll
  for (int u = 0; u < 4; ++u){
    float snd = (lane & 1) ? ph[u] : ph[u + 4];
    float t = __shfl_xor(snd, 1);
    ph[u] = ((lane & 1) ? ph[u + 4] : ph[u]) + t;
  }
#pragma unroll
  for (int u = 0; u < 2; ++u){
    float snd = (lane & 2) ? ph[u] : ph[u + 2];
    float t = __shfl_xor(snd, 2);
    ph[u] = ((lane & 2) ? ph[u + 2] : ph[u]) + t;
  }
  {
    float snd = (lane & 4) ? ph[0] : ph[1];
    float t = __shfl_xor(snd, 4);
    ph[0] = ((lane & 4) ? ph[1] : ph[0]) + t;
  }
  ph[0] += __shfl_xor(ph[0], 8);
  ph[0] += __shfl_xor(ph[0], 16);
  ph[0] += __shfl_xor(ph[0], 32);
  return ph[0];
}

// =================== K1a: pair LN -> bias b[h][i*512+j] (fp32) ===================
// grid 8192: block handles 32 rows r = i*512+j; wave handles 8 rows, 2 at a time
__global__ __launch_bounds__(256) void k1a_bias(const float* __restrict__ pair,
                                                const float* __restrict__ lnw,
                                                const float* __restrict__ lnb,
                                                const float* __restrict__ Wb,
                                                float* __restrict__ bbuf){
  __shared__ float bstage[32][9];
  const int tid = threadIdx.x, lane = tid & 63, wave = tid >> 6;
  const int r0 = blockIdx.x * 32;
  const int c0 = 2 * lane, c1 = 2 * lane + 1;
  float wb0[8], wb1[8];
#pragma unroll
  for (int h = 0; h < 8; ++h){ wb0[h] = Wb[c0 * 8 + h]; wb1[h] = Wb[c1 * 8 + h]; }
  const float lw0 = lnw[c0], lb0v = lnb[c0], lw1 = lnw[c1], lb1v = lnb[c1];
  const int hL = ((lane & 1) << 2) | (lane & 2) | ((lane >> 2) & 1);

#pragma unroll
  for (int it = 0; it < 4; ++it){
    const int rA = r0 + wave * 8 + it * 2;
    float2 xA = *(const float2*)(pair + (size_t)rA * 128 + c0);
    float2 xB = *(const float2*)(pair + ((size_t)rA + 1) * 128 + c0);
    float sA = xA.x + xA.y, qA = xA.x * xA.x + xA.y * xA.y;
    float sB = xB.x + xB.y, qB = xB.x * xB.x + xB.y * xB.y;
#pragma unroll
    for (int o = 1; o < 64; o <<= 1){
      sA += __shfl_xor(sA, o); qA += __shfl_xor(qA, o);
      sB += __shfl_xor(sB, o); qB += __shfl_xor(qB, o);
    }
    const float mA = sA * (1.f / 128.f), mB = sB * (1.f / 128.f);
    const float rsA = rsqrtf(qA * (1.f / 128.f) - mA * mA + 1e-5f);
    const float rsB = rsqrtf(qB * (1.f / 128.f) - mB * mB + 1e-5f);
    const float a0 = (xA.x - mA) * rsA * lw0 + lb0v;
    const float a1 = (xA.y - mA) * rsA * lw1 + lb1v;
    const float b0 = (xB.x - mB) * rsB * lw0 + lb0v;
    const float b1 = (xB.y - mB) * rsB * lw1 + lb1v;
    float phA[8], phB[8];
#pragma unroll
    for (int h = 0; h < 8; ++h){
      phA[h] = a0 * wb0[h] + a1 * wb1[h];
      phB[h] = b0 * wb0[h] + b1 * wb1[h];
    }
    float vA = fold8(phA, lane);
    float vB = fold8(phB, lane);
    if (lane < 8){
      bstage[wave * 8 + it * 2][hL]     = vA;
      bstage[wave * 8 + it * 2 + 1][hL] = vB;
    }
  }
  __syncthreads();
  { // coalesced write: b[h][r0+idx]
    int h = tid >> 5, idx = tid & 31;
    bbuf[(size_t)h * 262144 + r0 + idx] = bstage[idx][h];
  }
}

// =================== K1b: softmax over j -> w[h][i][j] bf16 ===================
// grid 1024: wave handles one row (h*512+i)
__global__ __launch_bounds__(256) void k1b_softmax(const float* __restrict__ bbuf,
                                                   unsigned short* __restrict__ wout){
  const int tid = threadIdx.x, lane = tid & 63, wave = tid >> 6;
  const int row = blockIdx.x * 4 + wave;
  const float* src = bbuf + (size_t)row * 512;
  float4 v0 = *(const float4*)(src + lane * 8);
  float4 v1 = *(const float4*)(src + lane * 8 + 4);
  float e[8] = {v0.x, v0.y, v0.z, v0.w, v1.x, v1.y, v1.z, v1.w};
  float m = e[0];
#pragma unroll
  for (int t = 1; t < 8; ++t) m = fmaxf(m, e[t]);
#pragma unroll
  for (int o = 1; o < 64; o <<= 1) m = fmaxf(m, __shfl_xor(m, o));
  float sum = 0.f;
#pragma unroll
  for (int t = 0; t < 8; ++t){ e[t] = __expf(e[t] - m); sum += e[t]; }
#pragma unroll
  for (int o = 1; o < 64; o <<= 1) sum += __shfl_xor(sum, o);
  const float inv = 1.0f / sum;
  unsigned int pk[4];
#pragma unroll
  for (int u = 0; u < 4; ++u)
    pk[u] = (unsigned)f2bf(e[u * 2] * inv) | ((unsigned)f2bf(e[u * 2 + 1] * inv) << 16);
  *(uint4*)(wout + (size_t)row * 512 + lane * 8) = make_uint4(pk[0], pk[1], pk[2], pk[3]);
}

// =================== K2: msa LN -> v = mn@Wv -> v_t[h][s*32+c][j] ===================
// grid (2048, 2): bx -> (s, n0), by -> 128-col slice of the 256 v-channels
__global__ __launch_bounds__(256) void k2_v(const float* __restrict__ msa,
                                            const float* __restrict__ lnw,
                                            const float* __restrict__ lnb,
                                            const unsigned short* __restrict__ wvt,
                                            unsigned short* __restrict__ vt){
  __shared__ unsigned short smem[18432];   // [0,9216): mnb [128][72]; [9216,18432): wvt slice [128][72]; epilogue overlay [128][136]
  __shared__ float lnw_s[64], lnb_s[64];
  const int tid = threadIdx.x, lane = tid & 63, wave = tid >> 6;
  const int bx = blockIdx.x;
  const int sIdx = bx >> 2, n0 = (bx & 3) * 128;
  const int cb = blockIdx.y * 128;
  const int g = lane >> 4, l15 = lane & 15;
  if (tid < 64){ lnw_s[tid] = lnw[tid]; lnb_s[tid] = lnb[tid]; }
  const int row = tid >> 1, half = tid & 1;
  float4 xv[8];
  {
    const float4* src = (const float4*)(msa + ((size_t)(sIdx * 512 + n0 + row)) * 64 + half * 32);
#pragma unroll
    for (int u = 0; u < 8; ++u) xv[u] = src[u];
  }
  { // stage Wv^T slice
    const uint4* src = (const uint4*)(wvt + (size_t)(cb + row) * 64 + half * 32);
    uint4* dst = (uint4*)&smem[9216 + row * 72 + half * 32];
#pragma unroll
    for (int u = 0; u < 4; ++u) dst[u] = src[u];
  }
  float sS = 0.f, qS = 0.f;
#pragma unroll
  for (int u = 0; u < 8; ++u){
    sS += xv[u].x + xv[u].y + xv[u].z + xv[u].w;
    qS += xv[u].x * xv[u].x + xv[u].y * xv[u].y + xv[u].z * xv[u].z + xv[u].w * xv[u].w;
  }
  sS += __shfl_xor(sS, 1); qS += __shfl_xor(qS, 1);
  const float mean = sS * (1.f / 64.f);
  const float var = qS * (1.f / 64.f) - mean * mean;
  const float rstd = rsqrtf(var + 1e-5f);
  __syncthreads();
  {
    unsigned int pk[16];
#pragma unroll
    for (int u = 0; u < 8; ++u){
      const int cbase = half * 32 + u * 4;
      float a0 = (xv[u].x - mean) * rstd * lnw_s[cbase + 0] + lnb_s[cbase + 0];
      float a1 = (xv[u].y - mean) * rstd * lnw_s[cbase + 1] + lnb_s[cbase + 1];
      float a2 = (xv[u].z - mean) * rstd * lnw_s[cbase + 2] + lnb_s[cbase + 2];
      float a3 = (xv[u].w - mean) * rstd * lnw_s[cbase + 3] + lnb_s[cbase + 3];
      pk[u * 2]     = (unsigned)f2bf(a0) | ((unsigned)f2bf(a1) << 16);
      pk[u * 2 + 1] = (unsigned)f2bf(a2) | ((unsigned)f2bf(a3) << 16);
    }
    uint4* dst = (uint4*)&smem[row * 72 + half * 32];
#pragma unroll
    for (int u = 0; u < 4; ++u) dst[u] = make_uint4(pk[u * 4], pk[u * 4 + 1], pk[u * 4 + 2], pk[u * 4 + 3]);
  }
  __syncthreads();
  const int wm = wave >> 1, wn = wave & 1;
  const f32x4 z = {0.f, 0.f, 0.f, 0.f};
  f32x4 acc[4][4];
#pragma unroll
  for (int a = 0; a < 4; ++a)
#pragma unroll
    for (int b = 0; b < 4; ++b) acc[a][b] = z;
#pragma unroll
  for (int kk = 0; kk < 64; kk += 32){
    bf16x8 av[4], bv[4];
#pragma unroll
    for (int mf = 0; mf < 4; ++mf){
      FragU f; f.u = *(const uint4*)&smem[(wm * 64 + mf * 16 + l15) * 72 + kk + 8 * g];
      av[mf] = f.v;
    }
#pragma unroll
    for (int nf = 0; nf < 4; ++nf){
      FragU f; f.u = *(const uint4*)&smem[9216 + (wn * 64 + nf * 16 + l15) * 72 + kk + 8 * g];
      bv[nf] = f.v;
    }
#pragma unroll
    for (int mf = 0; mf < 4; ++mf)
#pragma unroll
      for (int nf = 0; nf < 4; ++nf)
        acc[mf][nf] = __builtin_amdgcn_mfma_f32_16x16x32_bf16(av[mf], bv[nf], acc[mf][nf], 0, 0, 0);
  }
  __syncthreads();
  // epilogue transpose into overlay [hc][n]
#pragma unroll
  for (int nf = 0; nf < 4; ++nf){
    int hcL = wn * 64 + nf * 16 + l15;
#pragma unroll
    for (int mf = 0; mf < 4; ++mf){
      int nbase = wm * 64 + mf * 16 + 4 * g;
      u64 qv = (u64)f2bf(acc[mf][nf][0])
             | ((u64)f2bf(acc[mf][nf][1]) << 16)
             | ((u64)f2bf(acc[mf][nf][2]) << 32)
             | ((u64)f2bf(acc[mf][nf][3]) << 48);
      *(u64*)&smem[hcL * 136 + nbase] = qv;
    }
  }
  __syncthreads();
  { // coalesced global write: v_t[h][s*32+c][n]
    int hcL = tid >> 1, nh = tid & 1;
    int hc = cb + hcL;
    int hIdx = hc >> 5, c = hc & 31;
    unsigned short* dst = vt + ((size_t)(hIdx * 16384 + sIdx * 32 + c)) * 512 + n0 + nh * 64;
    const uint4* src = (const uint4*)&smem[hcL * 136 + nh * 64];
#pragma unroll
    for (int u = 0; u < 8; ++u) ((uint4*)dst)[u] = src[u];
  }
}

// =================== K3: per-head GEMM o[i, s*32+c] = sum_j w[h][i][j] * v_t[h][sc][j] ===================
// grid (128, 4, 8): bx -> sc-tile, by -> i-tile, bz -> head
__global__ __launch_bounds__(256) void k3_attn(const unsigned short* __restrict__ wp,
                                               const unsigned short* __restrict__ vt,
                                               unsigned short* __restrict__ o){
  __shared__ unsigned short A_s[128 * 72];
  __shared__ unsigned short B_s[128 * 72];
  const int tid = threadIdx.x, lane = tid & 63, wave = tid >> 6;
  const int sc0 = blockIdx.x * 128, i0 = blockIdx.y * 128, h = blockIdx.z;
  const int wm = wave >> 1, wn = wave & 1;
  const int g = lane >> 4, l15 = lane & 15;
  const int srow = tid >> 1, shalf = tid & 1;
  const unsigned short* wbase = wp + ((size_t)(h * 512 + i0 + srow)) * 512 + shalf * 32;
  const unsigned short* vbase = vt + ((size_t)(h * 16384 + sc0 + srow)) * 512 + shalf * 32;
  const f32x4 z = {0.f, 0.f, 0.f, 0.f};
  f32x4 acc[4][4];
#pragma unroll
  for (int a = 0; a < 4; ++a)
#pragma unroll
    for (int b = 0; b < 4; ++b) acc[a][b] = z;

  for (int kt = 0; kt < 8; ++kt){
    const int j0 = kt * 64;
    __syncthreads();
    {
      const uint4* ga = (const uint4*)(wbase + j0);
      uint4* da = (uint4*)&A_s[srow * 72 + shalf * 32];
#pragma unroll
      for (int u = 0; u < 4; ++u) da[u] = ga[u];
      const uint4* gb = (const uint4*)(vbase + j0);
      uint4* db = (uint4*)&B_s[srow * 72 + shalf * 32];
#pragma unroll
      for (int u = 0; u < 4; ++u) db[u] = gb[u];
    }
    __syncthreads();
#pragma unroll
    for (int kk = 0; kk < 64; kk += 32){
      bf16x8 av[4], bv[4];
#pragma unroll
      for (int mf = 0; mf < 4; ++mf){
        FragU f; f.u = *(const uint4*)&A_s[(wm * 64 + mf * 16 + l15) * 72 + kk + 8 * g];
        av[mf] = f.v;
      }
#pragma unroll
      for (int nf = 0; nf < 4; ++nf){
        FragU f; f.u = *(const uint4*)&B_s[(wn * 64 + nf * 16 + l15) * 72 + kk + 8 * g];
        bv[nf] = f.v;
      }
#pragma unroll
      for (int mf = 0; mf < 4; ++mf)
#pragma unroll
        for (int nf = 0; nf < 4; ++nf)
          acc[mf][nf] = __builtin_amdgcn_mfma_f32_16x16x32_bf16(av[mf], bv[nf], acc[mf][nf], 0, 0, 0);
    }
  }
  // epilogue: o[s][i][h*32+c]
#pragma unroll
  for (int nf = 0; nf < 4; ++nf){
    int col_sc = sc0 + wn * 64 + nf * 16 + l15;
    int sIdx = col_sc >> 5, c = col_sc & 31;
#pragma unroll
    for (int mf = 0; mf < 4; ++mf){
      int rbase = i0 + wm * 64 + mf * 16 + 4 * g;
#pragma unroll
      for (int e = 0; e < 4; ++e)
        o[((size_t)(sIdx * 512 + rbase + e)) * 256 + h * 32 + c] = f2bf(acc[mf][nf][e]);
    }
  }
}

// =================== K4: fused LN -> G=mn@Wg -> sigmoid -> gate*o -> @Wo -> out ===================
// grid 4096: 64 consecutive rows r = s*512 + i per block
__global__ __launch_bounds__(256) void k4_out(const float* __restrict__ msa,
                                              const float* __restrict__ lnw,
                                              const float* __restrict__ lnb,
                                              const unsigned short* __restrict__ ot,
                                              const unsigned short* __restrict__ wgt,
                                              const unsigned short* __restrict__ wot,
                                              float* __restrict__ out){
  __shared__ unsigned short o_s[64 * 256];
  __shared__ unsigned short mnb[64 * 72];
  __shared__ unsigned short X_s[64 * 40];
  __shared__ unsigned short wg_s[32 * 72];
  __shared__ unsigned short wo_s[64 * 40];
  __shared__ float lnw_s[64], lnb_s[64];
  const int tid = threadIdx.x, lane = tid & 63, wave = tid >> 6;
  const int r0 = blockIdx.x * 64;
  const int g = lane >> 4, l15 = lane & 15;
  if (tid < 64){ lnw_s[tid] = lnw[tid]; lnb_s[tid] = lnb[tid]; }
  { // stage o tile
    int row = tid >> 2, q = tid & 3;
    const uint4* src = (const uint4*)(ot + ((size_t)(r0 + row)) * 256 + q * 64);
    uint4* dst = (uint4*)&o_s[row * 256 + q * 64];
#pragma unroll
    for (int u = 0; u < 8; ++u) dst[u] = src[u];
  }
  // LayerNorm of msa rows (4 threads per row, 16 ch each)
  const int lrow = tid >> 2, lq = tid & 3;
  float4 xv[4];
  {
    const float4* src = (const float4*)(msa + ((size_t)(r0 + lrow)) * 64 + lq * 16);
#pragma unroll
    for (int u = 0; u < 4; ++u) xv[u] = src[u];
  }
  float sS = 0.f, qS = 0.f;
#pragma unroll
  for (int u = 0; u < 4; ++u){
    sS += xv[u].x + xv[u].y + xv[u].z + xv[u].w;
    qS += xv[u].x * xv[u].x + xv[u].y * xv[u].y + xv[u].z * xv[u].z + xv[u].w * xv[u].w;
  }
  sS += __shfl_xor(sS, 1); qS += __shfl_xor(qS, 1);
  sS += __shfl_xor(sS, 2); qS += __shfl_xor(qS, 2);
  const float mean = sS * (1.f / 64.f);
  const float var = qS * (1.f / 64.f) - mean * mean;
  const float rstd = rsqrtf(var + 1e-5f);
  __syncthreads();
  {
    unsigned int pk[8];
#pragma unroll
    for (int u = 0; u < 4; ++u){
      const int cbase = lq * 16 + u * 4;
      float a0 = (xv[u].x - mean) * rstd * lnw_s[cbase + 0] + lnb_s[cbase + 0];
      float a1 = (xv[u].y - mean) * rstd * lnw_s[cbase + 1] + lnb_s[cbase + 1];
      float a2 = (xv[u].z - mean) * rstd * lnw_s[cbase + 2] + lnb_s[cbase + 2];
      float a3 = (xv[u].w - mean) * rstd * lnw_s[cbase + 3] + lnb_s[cbase + 3];
      pk[u * 2]     = (unsigned)f2bf(a0) | ((unsigned)f2bf(a1) << 16);
      pk[u * 2 + 1] = (unsigned)f2bf(a2) | ((unsigned)f2bf(a3) << 16);
    }
    uint4* dst = (uint4*)&mnb[lrow * 72 + lq * 16];
    dst[0] = make_uint4(pk[0], pk[1], pk[2], pk[3]);
    dst[1] = make_uint4(pk[4], pk[5], pk[6], pk[7]);
  }
  const int wm = wave >> 1, wn = wave & 1;
  const f32x4 z = {0.f, 0.f, 0.f, 0.f};
  f32x4 accO[2][2];
  accO[0][0] = z; accO[0][1] = z; accO[1][0] = z; accO[1][1] = z;

  for (int h = 0; h < 8; ++h){
    __syncthreads();
    if (tid < 64){
      int row = tid >> 1, hf = tid & 1;
      const uint4* src = (const uint4*)(wgt + (size_t)(h * 32 + row) * 64 + hf * 32);
      uint4* dst = (uint4*)&wg_s[row * 72 + hf * 32];
#pragma unroll
      for (int u = 0; u < 4; ++u) dst[u] = src[u];
    } else if (tid < 192){
      int t = tid - 64; int row = t >> 1, hf = t & 1;
      const uint4* src = (const uint4*)(wot + (size_t)row * 256 + h * 32 + hf * 16);
      uint4* dst = (uint4*)&wo_s[row * 40 + hf * 16];
      dst[0] = src[0]; dst[1] = src[1];
    }
    __syncthreads();
    // G = mnb @ Wg_h  (wave handles rows [16w,16w+16), cols 0..31)
    f32x4 gacc[2]; gacc[0] = z; gacc[1] = z;
#pragma unroll
    for (int kk = 0; kk < 64; kk += 32){
      FragU a; a.u = *(const uint4*)&mnb[(wave * 16 + l15) * 72 + kk + 8 * g];
#pragma unroll
      for (int nf = 0; nf < 2; ++nf){
        FragU b; b.u = *(const uint4*)&wg_s[(nf * 16 + l15) * 72 + kk + 8 * g];
        gacc[nf] = __builtin_amdgcn_mfma_f32_16x16x32_bf16(a.v, b.v, gacc[nf], 0, 0, 0);
      }
    }
    // gate -> X_s
#pragma unroll
    for (int nf = 0; nf < 2; ++nf){
#pragma unroll
      for (int e = 0; e < 4; ++e){
        int row = wave * 16 + 4 * g + e;
        int col = nf * 16 + l15;
        float gv = 1.0f / (1.0f + __expf(-gacc[nf][e]));
        float ov = bf2f(o_s[row * 256 + h * 32 + col]);
        X_s[row * 40 + col] = f2bf(gv * ov);
      }
    }
    __syncthreads();
    // out += X_h @ Wo_h
#pragma unroll
    for (int mf = 0; mf < 2; ++mf){
      FragU a; a.u = *(const uint4*)&X_s[(wm * 32 + mf * 16 + l15) * 40 + 8 * g];
#pragma unroll
      for (int nf = 0; nf < 2; ++nf){
        FragU b; b.u = *(const uint4*)&wo_s[(wn * 32 + nf * 16 + l15) * 40 + 8 * g];
        accO[mf][nf] = __builtin_amdgcn_mfma_f32_16x16x32_bf16(a.v, b.v, accO[mf][nf], 0, 0, 0);
      }
    }
  }
#pragma unroll
  for (int mf = 0; mf < 2; ++mf)
#pragma unroll
    for (int nf = 0; nf < 2; ++nf)
#pragma unroll
      for (int e = 0; e < 4; ++e){
        int row = wm * 32 + mf * 16 + 4 * g + e;
        int col = wn * 32 + nf * 16 + l15;
        out[((size_t)(r0 + row)) * 64 + col] = accO[mf][nf][e];
      }
}

extern "C" void kernel_launch(void* const* d_in, const int* in_sizes, int n_in,
                              void* d_out, int out_size, void* d_ws, size_t ws_size,
                              hipStream_t stream){
  const float* msa       = (const float*)d_in[0];
  const float* pair      = (const float*)d_in[1];
  const float* ln_msa_w  = (const float*)d_in[2];
  const float* ln_msa_b  = (const float*)d_in[3];
  const float* ln_pair_w = (const float*)d_in[4];
  const float* ln_pair_b = (const float*)d_in[5];
  const float* Wv        = (const float*)d_in[6];
  const float* Wb        = (const float*)d_in[7];
  const float* Wg        = (const float*)d_in[8];
  const float* Wo        = (const float*)d_in[9];
  float* out = (float*)d_out;
  char* ws = (char*)d_ws;
  unsigned short* wvt = (unsigned short*)(ws + OFF_WVT);
  unsigned short* wgt = (unsigned short*)(ws + OFF_WGT);
  unsigned short* wot = (unsigned short*)(ws + OFF_WOT);
  unsigned short* wsm = (unsigned short*)(ws + OFF_W);
  unsigned short* vt  = (unsigned short*)(ws + OFF_VT);
  unsigned short* obuf= (unsigned short*)(ws + OFF_O);
  float* bbuf = (float*)(ws + OFF_VT);   // fp32 bias scratch, overwritten later by K2's vt

  hipLaunchKernelGGL(k0_weights,  dim3(192),        dim3(256), 0, stream, Wv, Wg, Wo, wvt, wgt, wot);
  hipLaunchKernelGGL(k1a_bias,    dim3(8192),       dim3(256), 0, stream, pair, ln_pair_w, ln_pair_b, Wb, bbuf);
  hipLaunchKernelGGL(k1b_softmax, dim3(1024),       dim3(256), 0, stream, bbuf, wsm);
  hipLaunchKernelGGL(k2_v,        dim3(2048, 2),    dim3(256), 0, stream, msa, ln_msa_w, ln_msa_b, wvt, vt);
  hipLaunchKernelGGL(k3_attn,     dim3(128, 4, 8),  dim3(256), 0, stream, wsm, vt, obuf);
  hipLaunchKernelGGL(k4_out,      dim3(4096),       dim3(256), 0, stream, msa, ln_msa_w, ln_msa_b, obuf, wgt, wot, out);
}